// Round 1
// baseline (666.072 us; speedup 1.0000x reference)
//
#include <hip/hip_runtime.h>

#define B_     64
#define T_     4096
#define DIM_   256
#define NFILT_ 32
#define KSIZE_ 31
#define PAD_   15
#define NEG_   -1e30f

// ---------------------------------------------------------------------------
// prep: blocks 0..63 compute q[b,:] = query[b,:] @ Wq^T   (one block per b)
//       block 64 computes M[d,k] = sum_f conv_w[f,0,k] * Wloc[d,f]
// ---------------------------------------------------------------------------
__global__ __launch_bounds__(256) void prep_kernel(
    const float* __restrict__ query, const float* __restrict__ Wq,
    const float* __restrict__ conv_w, const float* __restrict__ Wloc,
    float* __restrict__ q_ws, float* __restrict__ M_ws) {
  const int tid = threadIdx.x;
  if (blockIdx.x == 64) {
    __shared__ float cw[NFILT_ * KSIZE_];
    for (int i = tid; i < NFILT_ * KSIZE_; i += 256) cw[i] = conv_w[i];
    __syncthreads();
    const int d = tid;
    float wl[NFILT_];
#pragma unroll
    for (int f = 0; f < NFILT_; ++f) wl[f] = Wloc[d * NFILT_ + f];
#pragma unroll 4
    for (int k = 0; k < KSIZE_; ++k) {
      float acc = 0.f;
#pragma unroll
      for (int f = 0; f < NFILT_; ++f) acc = fmaf(cw[f * KSIZE_ + k], wl[f], acc);
      M_ws[d * KSIZE_ + k] = acc;
    }
  } else {
    const int b = blockIdx.x;
    __shared__ __align__(16) float qrow[DIM_];
    qrow[tid] = query[b * DIM_ + tid];
    __syncthreads();
    const int d = tid;
    const float4* Wq4 = (const float4*)(Wq + (size_t)d * DIM_);
    const float4* q4 = (const float4*)qrow;
    float acc = 0.f;
#pragma unroll 8
    for (int i = 0; i < DIM_ / 4; ++i) {
      float4 w = Wq4[i];
      float4 q = q4[i];
      acc = fmaf(w.x, q.x, acc);
      acc = fmaf(w.y, q.y, acc);
      acc = fmaf(w.z, q.z, acc);
      acc = fmaf(w.w, q.w, acc);
    }
    q_ws[b * DIM_ + d] = acc;
  }
}

// ---------------------------------------------------------------------------
// score: grid (16 chunks, 64 b), block 256 (thread = d).
// score[b,t] = sum_d tanh(q[b,d] + loc[b,t,d] + keys[b,t,d]) * v_w[d] + v_b
// loc via 31-tap FIR: loc = sum_k prev_pad[b,t+k] * M[d,k]
// Writes masked raw scores to align_out (softmaxed in place afterwards).
// ---------------------------------------------------------------------------
__global__ __launch_bounds__(256) void score_kernel(
    const float* __restrict__ keys, const float* __restrict__ prev,
    const int* __restrict__ mask, const float* __restrict__ v_w,
    const float* __restrict__ v_b, const float* __restrict__ q_ws,
    const float* __restrict__ M_ws, float* __restrict__ align_out) {
  const int TC = 256;
  const int chunk = blockIdx.x, b = blockIdx.y;
  const int t0 = chunk * TC;
  const int tid = threadIdx.x;
  const int d = tid;
  const int lane = tid & 63, wave = tid >> 6;

  __shared__ float prevs[TC + 2 * PAD_];
  __shared__ __align__(16) float red[TC * 4];

  // stage prev window [t0-PAD, t0+TC+PAD) with zero padding
  for (int i = tid; i < TC + 2 * PAD_; i += 256) {
    int g = t0 - PAD_ + i;
    prevs[i] = (g >= 0 && g < T_) ? prev[(size_t)b * T_ + g] : 0.f;
  }

  float m[KSIZE_];
#pragma unroll
  for (int k = 0; k < KSIZE_; ++k) m[k] = M_ws[d * KSIZE_ + k];
  const float qd = q_ws[b * DIM_ + d];
  const float vwd = v_w[d];
  __syncthreads();

  const float* krow = keys + ((size_t)b * T_ + t0) * DIM_ + d;
#pragma unroll 2
  for (int tl = 0; tl < TC; ++tl) {
    float key = krow[(size_t)tl * DIM_];
    float loc = 0.f;
#pragma unroll
    for (int k = 0; k < KSIZE_; ++k) loc = fmaf(prevs[tl + k], m[k], loc);
    float x = qd + loc + key;
    // tanh(x) = 1 - 2/(exp(2x)+1)
    float e = __expf(2.f * x);
    float th = 1.f - __fdividef(2.f, e + 1.f);
    float c = th * vwd;
#pragma unroll
    for (int off = 32; off > 0; off >>= 1) c += __shfl_xor(c, off, 64);
    if (lane == 0) red[tl * 4 + wave] = c;
  }
  __syncthreads();

  {
    const int tl = tid;
    float4 r = ((const float4*)red)[tl];
    float s = r.x + r.y + r.z + r.w + v_b[0];
    int t = t0 + tl;
    float sc = mask[(size_t)b * T_ + t] ? NEG_ : s;
    align_out[(size_t)b * T_ + t] = sc;
  }
}

// ---------------------------------------------------------------------------
// softmax in place over T per batch row. 64 blocks x 256 threads, 16 elems/thr.
// ---------------------------------------------------------------------------
__global__ __launch_bounds__(256) void softmax_kernel(float* __restrict__ align) {
  const int b = blockIdx.x, tid = threadIdx.x;
  const int lane = tid & 63, wave = tid >> 6;
  float* row = align + (size_t)b * T_;
  float v[16];
  float mx = -__builtin_inff();
#pragma unroll
  for (int i = 0; i < 16; ++i) {
    v[i] = row[tid + i * 256];
    mx = fmaxf(mx, v[i]);
  }
  __shared__ float redm[4];
  __shared__ float reds[4];
#pragma unroll
  for (int off = 32; off > 0; off >>= 1) mx = fmaxf(mx, __shfl_xor(mx, off, 64));
  if (lane == 0) redm[wave] = mx;
  __syncthreads();
  mx = fmaxf(fmaxf(redm[0], redm[1]), fmaxf(redm[2], redm[3]));
  float s = 0.f;
#pragma unroll
  for (int i = 0; i < 16; ++i) {
    v[i] = __expf(v[i] - mx);
    s += v[i];
  }
#pragma unroll
  for (int off = 32; off > 0; off >>= 1) s += __shfl_xor(s, off, 64);
  if (lane == 0) reds[wave] = s;
  __syncthreads();
  s = reds[0] + reds[1] + reds[2] + reds[3];
  float inv = __fdividef(1.f, s);
#pragma unroll
  for (int i = 0; i < 16; ++i) row[tid + i * 256] = v[i] * inv;
}

// ---------------------------------------------------------------------------
// context: attention[b,d] = sum_t align[b,t] * values[b,t,d]
// grid (16 chunks, 64 b), block 256: wave w owns t = base+4i+w, lane l owns
// d = 4l..4l+3 (float4 coalesced). Cross-wave LDS reduce, atomicAdd to out.
// ---------------------------------------------------------------------------
__global__ __launch_bounds__(256) void context_kernel(
    const float* __restrict__ values, const float* __restrict__ align,
    float* __restrict__ attn_out) {
  const int TC = 256;
  const int b = blockIdx.y;
  const int t0 = blockIdx.x * TC;
  const int tid = threadIdx.x, lane = tid & 63, wave = tid >> 6;
  float4 acc = make_float4(0.f, 0.f, 0.f, 0.f);
  const float4* vals = (const float4*)values;
  const float* al = align + (size_t)b * T_ + t0;
#pragma unroll 4
  for (int it = 0; it < TC / 4; ++it) {
    int tl = it * 4 + wave;
    float a = al[tl];
    float4 v = vals[((size_t)b * T_ + t0 + tl) * (DIM_ / 4) + lane];
    acc.x = fmaf(a, v.x, acc.x);
    acc.y = fmaf(a, v.y, acc.y);
    acc.z = fmaf(a, v.z, acc.z);
    acc.w = fmaf(a, v.w, acc.w);
  }
  __shared__ __align__(16) float red[4 * DIM_];
  ((float4*)red)[wave * 64 + lane] = acc;
  __syncthreads();
  const int d = tid;
  float s = red[0 * DIM_ + d] + red[1 * DIM_ + d] + red[2 * DIM_ + d] +
            red[3 * DIM_ + d];
  atomicAdd(&attn_out[b * DIM_ + d], s);
}

extern "C" void kernel_launch(void* const* d_in, const int* in_sizes, int n_in,
                              void* d_out, int out_size, void* d_ws,
                              size_t ws_size, hipStream_t stream) {
  const float* query = (const float*)d_in[0];
  const float* keys = (const float*)d_in[1];
  const float* values = (const float*)d_in[2];
  const float* prev = (const float*)d_in[3];
  const int* mask = (const int*)d_in[4];
  const float* Wq = (const float*)d_in[5];
  const float* conv_w = (const float*)d_in[6];
  const float* Wloc = (const float*)d_in[7];
  const float* v_w = (const float*)d_in[8];
  const float* v_b = (const float*)d_in[9];

  float* attn_out = (float*)d_out;                 // B*DIM
  float* align_out = (float*)d_out + B_ * DIM_;    // B*T
  float* q_ws = (float*)d_ws;                      // B*DIM floats
  float* M_ws = q_ws + B_ * DIM_;                  // DIM*KSIZE floats

  hipMemsetAsync(attn_out, 0, B_ * DIM_ * sizeof(float), stream);
  prep_kernel<<<65, 256, 0, stream>>>(query, Wq, conv_w, Wloc, q_ws, M_ws);
  score_kernel<<<dim3(16, 64), 256, 0, stream>>>(keys, prev, mask, v_w, v_b,
                                                 q_ws, M_ws, align_out);
  softmax_kernel<<<64, 256, 0, stream>>>(align_out);
  context_kernel<<<dim3(16, 64), 256, 0, stream>>>(values, align_out, attn_out);
}

// Round 2
// 571.031 us; speedup vs baseline: 1.1664x; 1.1664x over previous
//
#include <hip/hip_runtime.h>

#define B_     64
#define T_     4096
#define DIM_   256
#define NFILT_ 32
#define KSIZE_ 31
#define PAD_   15
#define NEG_   -1e30f
#define TCB_   256   // t per block in score kernel
#define TT_    32    // t per LDS reduce tile
#define CS_    257   // padded c_s row stride (257 % 32 == 1 -> conflict-free)

// ---------------------------------------------------------------------------
// prep: blocks 0..63 compute q[b,:] = query[b,:] @ Wq^T   (one block per b)
//       block 64 computes M[d,k] = sum_f conv_w[f,0,k] * Wloc[d,f]
// ---------------------------------------------------------------------------
__global__ __launch_bounds__(256) void prep_kernel(
    const float* __restrict__ query, const float* __restrict__ Wq,
    const float* __restrict__ conv_w, const float* __restrict__ Wloc,
    float* __restrict__ q_ws, float* __restrict__ M_ws) {
  const int tid = threadIdx.x;
  if (blockIdx.x == 64) {
    __shared__ float cw[NFILT_ * KSIZE_];
    for (int i = tid; i < NFILT_ * KSIZE_; i += 256) cw[i] = conv_w[i];
    __syncthreads();
    const int d = tid;
    float wl[NFILT_];
#pragma unroll
    for (int f = 0; f < NFILT_; ++f) wl[f] = Wloc[d * NFILT_ + f];
#pragma unroll 4
    for (int k = 0; k < KSIZE_; ++k) {
      float acc = 0.f;
#pragma unroll
      for (int f = 0; f < NFILT_; ++f) acc = fmaf(cw[f * KSIZE_ + k], wl[f], acc);
      M_ws[d * KSIZE_ + k] = acc;
    }
  } else {
    const int b = blockIdx.x;
    __shared__ __align__(16) float qrow[DIM_];
    qrow[tid] = query[b * DIM_ + tid];
    __syncthreads();
    const int d = tid;
    const float4* Wq4 = (const float4*)(Wq + (size_t)d * DIM_);
    const float4* q4 = (const float4*)qrow;
    float acc = 0.f;
#pragma unroll 8
    for (int i = 0; i < DIM_ / 4; ++i) {
      float4 w = Wq4[i];
      float4 q = q4[i];
      acc = fmaf(w.x, q.x, acc);
      acc = fmaf(w.y, q.y, acc);
      acc = fmaf(w.z, q.z, acc);
      acc = fmaf(w.w, q.w, acc);
    }
    q_ws[b * DIM_ + d] = acc;
  }
}

// ---------------------------------------------------------------------------
// score: grid (16, 64), block 256 (thread = d). LDS transpose reduce, no
// shuffles. Mask-skip: masked t (wave-uniform) skip keys load + FIR + tanh.
// score[b,t] = sum_d tanh(q[b,d] + loc[b,t,d] + keys[b,t,d]) * v_w[d] + v_b
// ---------------------------------------------------------------------------
__global__ __launch_bounds__(256) void score_kernel(
    const float* __restrict__ keys, const float* __restrict__ prev,
    const int* __restrict__ mask, const float* __restrict__ v_w,
    const float* __restrict__ v_b, const float* __restrict__ q_ws,
    const float* __restrict__ M_ws, float* __restrict__ align_out) {
  const int chunk = blockIdx.x, b = blockIdx.y;
  const int t0 = chunk * TCB_;
  const int tid = threadIdx.x;
  const int d = tid;

  __shared__ float prevs[TCB_ + 2 * PAD_];
  __shared__ int msk[TCB_];
  __shared__ float c_s[TT_ * CS_];     // [t][d], stride 257
  __shared__ float partial[TT_ * 9];   // [t][part], stride 9

  for (int i = tid; i < TCB_ + 2 * PAD_; i += 256) {
    int g = t0 - PAD_ + i;
    prevs[i] = (g >= 0 && g < T_) ? prev[(size_t)b * T_ + g] : 0.f;
  }
  msk[tid] = mask[(size_t)b * T_ + t0 + tid];

  float m[KSIZE_];
#pragma unroll
  for (int k = 0; k < KSIZE_; ++k) m[k] = M_ws[d * KSIZE_ + k];
  const float qd = q_ws[b * DIM_ + d];
  const float vwd = v_w[d];
  const float vb = v_b[0];
  __syncthreads();

  const float* kbase = keys + ((size_t)b * T_ + t0) * DIM_ + d;

  for (int tile = 0; tile < TCB_ / TT_; ++tile) {
    const int tb = tile * TT_;

    // ---- compute phase (1-deep keys prefetch, mask-aware) ----
    bool skip_n = msk[tb] != 0;
    float key_n = 0.f;
    if (!skip_n) key_n = kbase[(size_t)tb * DIM_];
    for (int tl = 0; tl < TT_; ++tl) {
      bool skip = skip_n;
      float key = key_n;
      if (tl + 1 < TT_) {
        skip_n = msk[tb + tl + 1] != 0;
        if (!skip_n) key_n = kbase[(size_t)(tb + tl + 1) * DIM_];
      }
      if (!skip) {
        const float* pw = prevs + tb + tl;
        float l0 = 0.f, l1 = 0.f, l2 = 0.f, l3 = 0.f;
#pragma unroll
        for (int k = 0; k < 28; k += 4) {
          l0 = fmaf(pw[k], m[k], l0);
          l1 = fmaf(pw[k + 1], m[k + 1], l1);
          l2 = fmaf(pw[k + 2], m[k + 2], l2);
          l3 = fmaf(pw[k + 3], m[k + 3], l3);
        }
        l0 = fmaf(pw[28], m[28], l0);
        l1 = fmaf(pw[29], m[29], l1);
        l2 = fmaf(pw[30], m[30], l2);
        float x = qd + (l0 + l1) + (l2 + l3) + key;
        // tanh(x) = 1 - 2/(exp(2x)+1)
        float e = __expf(2.f * x);
        float th = 1.f - __fdividef(2.f, e + 1.f);
        c_s[tl * CS_ + d] = th * vwd;
      }
    }
    __syncthreads();

    // ---- reduce phase: thread (t = tid&31, part = tid>>5) sums 32 d ----
    {
      const int t = tid & 31, part = tid >> 5;
      const float* row = c_s + t * CS_ + part * 32;
      float s0 = 0.f, s1 = 0.f, s2 = 0.f, s3 = 0.f;
#pragma unroll
      for (int j = 0; j < 32; j += 4) {
        s0 += row[j];
        s1 += row[j + 1];
        s2 += row[j + 2];
        s3 += row[j + 3];
      }
      partial[t * 9 + part] = (s0 + s1) + (s2 + s3);
    }
    __syncthreads();

    // ---- final: 32 threads write scores ----
    if (tid < TT_) {
      const float* pr = partial + tid * 9;
      float s = ((pr[0] + pr[1]) + (pr[2] + pr[3])) +
                ((pr[4] + pr[5]) + (pr[6] + pr[7]));
      int t = t0 + tb + tid;
      align_out[(size_t)b * T_ + t] = msk[tb + tid] ? NEG_ : (s + vb);
    }
    // next compute phase only writes c_s (reads done before last sync);
    // next partial write is after the next __syncthreads -> safe.
  }
}

// ---------------------------------------------------------------------------
// softmax in place over T per batch row. 64 blocks x 256 threads, 16 elems/thr.
// ---------------------------------------------------------------------------
__global__ __launch_bounds__(256) void softmax_kernel(float* __restrict__ align) {
  const int b = blockIdx.x, tid = threadIdx.x;
  const int lane = tid & 63, wave = tid >> 6;
  float* row = align + (size_t)b * T_;
  float v[16];
  float mx = -__builtin_inff();
#pragma unroll
  for (int i = 0; i < 16; ++i) {
    v[i] = row[tid + i * 256];
    mx = fmaxf(mx, v[i]);
  }
  __shared__ float redm[4];
  __shared__ float reds[4];
#pragma unroll
  for (int off = 32; off > 0; off >>= 1) mx = fmaxf(mx, __shfl_xor(mx, off, 64));
  if (lane == 0) redm[wave] = mx;
  __syncthreads();
  mx = fmaxf(fmaxf(redm[0], redm[1]), fmaxf(redm[2], redm[3]));
  float s = 0.f;
#pragma unroll
  for (int i = 0; i < 16; ++i) {
    v[i] = __expf(v[i] - mx);
    s += v[i];
  }
#pragma unroll
  for (int off = 32; off > 0; off >>= 1) s += __shfl_xor(s, off, 64);
  if (lane == 0) reds[wave] = s;
  __syncthreads();
  s = reds[0] + reds[1] + reds[2] + reds[3];
  float inv = __fdividef(1.f, s);
#pragma unroll
  for (int i = 0; i < 16; ++i) row[tid + i * 256] = v[i] * inv;
}

// ---------------------------------------------------------------------------
// context: attention[b,d] = sum_t align[b,t] * values[b,t,d]
// grid (16, 64), block 256. Wave w owns t = w*64..w*64+63; lane owns d-quad.
// Zero-skip: align[t]==0 (masked after softmax) -> skip the float4 load.
// ---------------------------------------------------------------------------
__global__ __launch_bounds__(256) void context_kernel(
    const float* __restrict__ values, const float* __restrict__ align,
    float* __restrict__ attn_out) {
  const int TC = 256;
  const int b = blockIdx.y;
  const int t0 = blockIdx.x * TC;
  const int tid = threadIdx.x, lane = tid & 63, wave = tid >> 6;

  __shared__ float als[TC];
  als[tid] = align[(size_t)b * T_ + t0 + tid];
  __syncthreads();

  float4 acc = make_float4(0.f, 0.f, 0.f, 0.f);
  const float4* vals = (const float4*)(values + ((size_t)b * T_ + t0) * DIM_);
#pragma unroll 2
  for (int j = 0; j < 64; ++j) {
    int tl = wave * 64 + j;
    float a = als[tl];
    if (a != 0.f) {
      float4 v = vals[(size_t)tl * (DIM_ / 4) + lane];
      acc.x = fmaf(a, v.x, acc.x);
      acc.y = fmaf(a, v.y, acc.y);
      acc.z = fmaf(a, v.z, acc.z);
      acc.w = fmaf(a, v.w, acc.w);
    }
  }
  __shared__ __align__(16) float red[4 * DIM_];
  ((float4*)red)[wave * 64 + lane] = acc;
  __syncthreads();
  const int dd = tid;
  float s = red[0 * DIM_ + dd] + red[1 * DIM_ + dd] + red[2 * DIM_ + dd] +
            red[3 * DIM_ + dd];
  atomicAdd(&attn_out[b * DIM_ + dd], s);
}

extern "C" void kernel_launch(void* const* d_in, const int* in_sizes, int n_in,
                              void* d_out, int out_size, void* d_ws,
                              size_t ws_size, hipStream_t stream) {
  const float* query = (const float*)d_in[0];
  const float* keys = (const float*)d_in[1];
  const float* values = (const float*)d_in[2];
  const float* prev = (const float*)d_in[3];
  const int* mask = (const int*)d_in[4];
  const float* Wq = (const float*)d_in[5];
  const float* conv_w = (const float*)d_in[6];
  const float* Wloc = (const float*)d_in[7];
  const float* v_w = (const float*)d_in[8];
  const float* v_b = (const float*)d_in[9];

  float* attn_out = (float*)d_out;               // B*DIM
  float* align_out = (float*)d_out + B_ * DIM_;  // B*T
  float* q_ws = (float*)d_ws;                    // B*DIM floats
  float* M_ws = q_ws + B_ * DIM_;                // DIM*KSIZE floats

  hipMemsetAsync(attn_out, 0, B_ * DIM_ * sizeof(float), stream);
  prep_kernel<<<65, 256, 0, stream>>>(query, Wq, conv_w, Wloc, q_ws, M_ws);
  score_kernel<<<dim3(16, 64), 256, 0, stream>>>(keys, prev, mask, v_w, v_b,
                                                 q_ws, M_ws, align_out);
  softmax_kernel<<<64, 256, 0, stream>>>(align_out);
  context_kernel<<<dim3(16, 64), 256, 0, stream>>>(values, align_out, attn_out);
}

// Round 3
// 545.863 us; speedup vs baseline: 1.2202x; 1.0461x over previous
//
#include <hip/hip_runtime.h>

#define B_     64
#define T_     4096
#define DIM_   256
#define NFILT_ 32
#define KSIZE_ 31
#define PAD_   15
#define NEG_   -1e30f
#define TCB_   256   // t per block in score kernel
#define TT_    32    // t per LDS reduce tile
#define WS_    (TT_ + KSIZE_ - 1)  // 63-tap uniform prev window per tile
#define CS_    257   // padded c_s row stride (257 % 32 == 1 -> conflict-free)

// ---------------------------------------------------------------------------
// prep: blocks 0..63 compute q[b,:] = query[b,:] @ Wq^T   (one block per b)
//       block 64 computes M[d,k] = sum_f conv_w[f,0,k] * Wloc[d,f]
// ---------------------------------------------------------------------------
__global__ __launch_bounds__(256) void prep_kernel(
    const float* __restrict__ query, const float* __restrict__ Wq,
    const float* __restrict__ conv_w, const float* __restrict__ Wloc,
    float* __restrict__ q_ws, float* __restrict__ M_ws) {
  const int tid = threadIdx.x;
  if (blockIdx.x == 64) {
    __shared__ float cw[NFILT_ * KSIZE_];
    for (int i = tid; i < NFILT_ * KSIZE_; i += 256) cw[i] = conv_w[i];
    __syncthreads();
    const int d = tid;
    float wl[NFILT_];
#pragma unroll
    for (int f = 0; f < NFILT_; ++f) wl[f] = Wloc[d * NFILT_ + f];
#pragma unroll 4
    for (int k = 0; k < KSIZE_; ++k) {
      float acc = 0.f;
#pragma unroll
      for (int f = 0; f < NFILT_; ++f) acc = fmaf(cw[f * KSIZE_ + k], wl[f], acc);
      M_ws[d * KSIZE_ + k] = acc;
    }
  } else {
    const int b = blockIdx.x;
    __shared__ __align__(16) float qrow[DIM_];
    qrow[tid] = query[b * DIM_ + tid];
    __syncthreads();
    const int d = tid;
    const float4* Wq4 = (const float4*)(Wq + (size_t)d * DIM_);
    const float4* q4 = (const float4*)qrow;
    float acc = 0.f;
#pragma unroll 8
    for (int i = 0; i < DIM_ / 4; ++i) {
      float4 w = Wq4[i];
      float4 q = q4[i];
      acc = fmaf(w.x, q.x, acc);
      acc = fmaf(w.y, q.y, acc);
      acc = fmaf(w.z, q.z, acc);
      acc = fmaf(w.w, q.w, acc);
    }
    q_ws[b * DIM_ + d] = acc;
  }
}

// ---------------------------------------------------------------------------
// score: grid (16, 64), block 256 (thread = d).
// FIR window is wave-uniform -> loaded as uniform (scalar) register window W
// per 32-t tile; FIR = 31 register FMAs. Keys prefetched 4-deep. Mask-skip
// (wave-uniform) skips keys load + FIR + tanh. LDS transpose reduce.
// ---------------------------------------------------------------------------
__global__ __launch_bounds__(256) void score_kernel(
    const float* __restrict__ keys, const float* __restrict__ prev,
    const int* __restrict__ mask, const float* __restrict__ v_w,
    const float* __restrict__ v_b, const float* __restrict__ q_ws,
    const float* __restrict__ M_ws, float* __restrict__ align_out) {
  const int chunk = blockIdx.x, b = blockIdx.y;
  const int t0 = chunk * TCB_;
  const int tid = threadIdx.x;
  const int d = tid;

  __shared__ int msk[TCB_];
  __shared__ float c_s[TT_ * CS_];     // [t][d], stride 257
  __shared__ float partial[TT_ * 9];   // [t][part], stride 9

  msk[tid] = mask[(size_t)b * T_ + t0 + tid];

  float m[KSIZE_];
#pragma unroll
  for (int k = 0; k < KSIZE_; ++k) m[k] = M_ws[d * KSIZE_ + k];
  const float qd = q_ws[b * DIM_ + d];
  const float vwd = v_w[d];
  const float vb = v_b[0];
  __syncthreads();

  const float* kbase = keys + ((size_t)b * T_ + t0) * DIM_ + d;
  const float* prow = prev + (size_t)b * T_;

  for (int tile = 0; tile < TCB_ / TT_; ++tile) {
    const int tb = tile * TT_;

    // ---- uniform prev window (should scalarize to s_load: addr is
    //      blockIdx/tile-derived, memory is const __restrict__) ----
    float W[WS_];
#pragma unroll
    for (int j = 0; j < WS_; ++j) {
      int g = t0 + tb - PAD_ + j;
      W[j] = (g >= 0 && g < T_) ? prow[g] : 0.f;
    }

    // ---- compute phase: groups of 4 t, 4-deep keys prefetch ----
#pragma unroll
    for (int g4 = 0; g4 < TT_; g4 += 4) {
      float kv[4];
      bool sk[4];
#pragma unroll
      for (int u = 0; u < 4; ++u) {
        sk[u] = msk[tb + g4 + u] != 0;
        kv[u] = 0.f;
        if (!sk[u]) kv[u] = kbase[(size_t)(tb + g4 + u) * DIM_];
      }
#pragma unroll
      for (int u = 0; u < 4; ++u) {
        if (!sk[u]) {
          const int tl = g4 + u;
          float l0 = qd + kv[u], l1 = 0.f, l2 = 0.f, l3 = 0.f;
#pragma unroll
          for (int k = 0; k < 28; k += 4) {
            l0 = fmaf(W[tl + k], m[k], l0);
            l1 = fmaf(W[tl + k + 1], m[k + 1], l1);
            l2 = fmaf(W[tl + k + 2], m[k + 2], l2);
            l3 = fmaf(W[tl + k + 3], m[k + 3], l3);
          }
          l0 = fmaf(W[tl + 28], m[28], l0);
          l1 = fmaf(W[tl + 29], m[29], l1);
          l2 = fmaf(W[tl + 30], m[30], l2);
          float x = (l0 + l1) + (l2 + l3);
          // tanh(x) = 1 - 2/(exp(2x)+1)
          float e = __expf(2.f * x);
          float th = 1.f - __fdividef(2.f, e + 1.f);
          c_s[tl * CS_ + d] = th * vwd;
        }
      }
    }
    __syncthreads();

    // ---- reduce phase: thread (t = tid&31, part = tid>>5) sums 32 d ----
    {
      const int t = tid & 31, part = tid >> 5;
      const float* row = c_s + t * CS_ + part * 32;
      float s0 = 0.f, s1 = 0.f, s2 = 0.f, s3 = 0.f;
#pragma unroll
      for (int j = 0; j < 32; j += 4) {
        s0 += row[j];
        s1 += row[j + 1];
        s2 += row[j + 2];
        s3 += row[j + 3];
      }
      partial[t * 9 + part] = (s0 + s1) + (s2 + s3);
    }
    __syncthreads();

    // ---- final: 32 threads write scores ----
    if (tid < TT_) {
      const float* pr = partial + tid * 9;
      float s = ((pr[0] + pr[1]) + (pr[2] + pr[3])) +
                ((pr[4] + pr[5]) + (pr[6] + pr[7]));
      int t = t0 + tb + tid;
      align_out[(size_t)b * T_ + t] = msk[tb + tid] ? NEG_ : (s + vb);
    }
  }
}

// ---------------------------------------------------------------------------
// softmax in place over T per batch row. 64 blocks x 256 threads, 16 elems/thr.
// ---------------------------------------------------------------------------
__global__ __launch_bounds__(256) void softmax_kernel(float* __restrict__ align) {
  const int b = blockIdx.x, tid = threadIdx.x;
  const int lane = tid & 63, wave = tid >> 6;
  float* row = align + (size_t)b * T_;
  float v[16];
  float mx = -__builtin_inff();
#pragma unroll
  for (int i = 0; i < 16; ++i) {
    v[i] = row[tid + i * 256];
    mx = fmaxf(mx, v[i]);
  }
  __shared__ float redm[4];
  __shared__ float reds[4];
#pragma unroll
  for (int off = 32; off > 0; off >>= 1) mx = fmaxf(mx, __shfl_xor(mx, off, 64));
  if (lane == 0) redm[wave] = mx;
  __syncthreads();
  mx = fmaxf(fmaxf(redm[0], redm[1]), fmaxf(redm[2], redm[3]));
  float s = 0.f;
#pragma unroll
  for (int i = 0; i < 16; ++i) {
    v[i] = __expf(v[i] - mx);
    s += v[i];
  }
#pragma unroll
  for (int off = 32; off > 0; off >>= 1) s += __shfl_xor(s, off, 64);
  if (lane == 0) reds[wave] = s;
  __syncthreads();
  s = reds[0] + reds[1] + reds[2] + reds[3];
  float inv = __fdividef(1.f, s);
#pragma unroll
  for (int i = 0; i < 16; ++i) row[tid + i * 256] = v[i] * inv;
}

// ---------------------------------------------------------------------------
// context: attention[b,d] = sum_t align[b,t] * values[b,t,d]
// grid (16, 64), block 256. Wave w owns t = w*64..w*64+63; lane owns d-quad.
// Zero-skip: align[t]==0 (masked after softmax) -> skip the float4 load.
// 4-deep unroll for independent outstanding loads.
// ---------------------------------------------------------------------------
__global__ __launch_bounds__(256) void context_kernel(
    const float* __restrict__ values, const float* __restrict__ align,
    float* __restrict__ attn_out) {
  const int TC = 256;
  const int b = blockIdx.y;
  const int t0 = blockIdx.x * TC;
  const int tid = threadIdx.x, lane = tid & 63, wave = tid >> 6;

  __shared__ float als[TC];
  als[tid] = align[(size_t)b * T_ + t0 + tid];
  __syncthreads();

  float4 acc = make_float4(0.f, 0.f, 0.f, 0.f);
  const float4* vals = (const float4*)(values + ((size_t)b * T_ + t0) * DIM_);
#pragma unroll
  for (int j = 0; j < 64; j += 4) {
    float a[4];
    float4 v[4];
#pragma unroll
    for (int u = 0; u < 4; ++u) {
      a[u] = als[wave * 64 + j + u];
      v[u] = make_float4(0.f, 0.f, 0.f, 0.f);
      if (a[u] != 0.f)
        v[u] = vals[(size_t)(wave * 64 + j + u) * (DIM_ / 4) + lane];
    }
#pragma unroll
    for (int u = 0; u < 4; ++u) {
      acc.x = fmaf(a[u], v[u].x, acc.x);
      acc.y = fmaf(a[u], v[u].y, acc.y);
      acc.z = fmaf(a[u], v[u].z, acc.z);
      acc.w = fmaf(a[u], v[u].w, acc.w);
    }
  }
  __shared__ __align__(16) float red[4 * DIM_];
  ((float4*)red)[wave * 64 + lane] = acc;
  __syncthreads();
  const int dd = tid;
  float s = red[0 * DIM_ + dd] + red[1 * DIM_ + dd] + red[2 * DIM_ + dd] +
            red[3 * DIM_ + dd];
  atomicAdd(&attn_out[b * DIM_ + dd], s);
}

extern "C" void kernel_launch(void* const* d_in, const int* in_sizes, int n_in,
                              void* d_out, int out_size, void* d_ws,
                              size_t ws_size, hipStream_t stream) {
  const float* query = (const float*)d_in[0];
  const float* keys = (const float*)d_in[1];
  const float* values = (const float*)d_in[2];
  const float* prev = (const float*)d_in[3];
  const int* mask = (const int*)d_in[4];
  const float* Wq = (const float*)d_in[5];
  const float* conv_w = (const float*)d_in[6];
  const float* Wloc = (const float*)d_in[7];
  const float* v_w = (const float*)d_in[8];
  const float* v_b = (const float*)d_in[9];

  float* attn_out = (float*)d_out;               // B*DIM
  float* align_out = (float*)d_out + B_ * DIM_;  // B*T
  float* q_ws = (float*)d_ws;                    // B*DIM floats
  float* M_ws = q_ws + B_ * DIM_;                // DIM*KSIZE floats

  hipMemsetAsync(attn_out, 0, B_ * DIM_ * sizeof(float), stream);
  prep_kernel<<<65, 256, 0, stream>>>(query, Wq, conv_w, Wloc, q_ws, M_ws);
  score_kernel<<<dim3(16, 64), 256, 0, stream>>>(keys, prev, mask, v_w, v_b,
                                                 q_ws, M_ws, align_out);
  softmax_kernel<<<64, 256, 0, stream>>>(align_out);
  context_kernel<<<dim3(16, 64), 256, 0, stream>>>(values, align_out, attn_out);
}